// Round 5
// baseline (101.643 us; speedup 1.0000x reference)
//
#include <hip/hip_runtime.h>
#include <hip/hip_bf16.h>

#define DIM 384
#define BATCH 1024
#define SPLANE (DIM * DIM)

// f32 -> bf16 bits, round-to-nearest-even (finite inputs)
__device__ __forceinline__ unsigned tobf(float x) {
    unsigned u = __float_as_uint(x);
    return (u + 0x7fffu + ((u >> 16) & 1u)) >> 16;
}
__device__ __forceinline__ float bflo(unsigned u) { return __uint_as_float(u << 16); }
__device__ __forceinline__ float bfhi(unsigned u) { return __uint_as_float(u & 0xffff0000u); }

// ---------------------------------------------------------------------------
// Kernel 1 (prep_all), grid = 120 blocks x 384 threads, two roles:
//
// Blocks 0..95  : rows i0=4*bx .. i0+3 of the folded block-affine product.
//   Pq[bx*2*DIM + 2j]   = pack(p(i0,j),   p(i0+1,j))        p = rw[i]*prod(1-Wk)
//   Pq[bx*2*DIM + 2j+1] = pack(p(i0+2,j), p(i0+3,j))
//   qpart[bx*DIM + j]   = sum_{i in quad} rw[i]*q(i,j)      (no atomics)
//
// Blocks 96..119: transpose-pack lin_W into k-quads:
//   Wtq[(j/4)*2*DIM + 2n]   = pack(lW[n][j],   lW[n][j+1])
//   Wtq[(j/4)*2*DIM + 2n+1] = pack(lW[n][j+2], lW[n][j+3])
// ---------------------------------------------------------------------------
__global__ __launch_bounds__(384)
void prep_all(const float* __restrict__ W,
              const float* __restrict__ Bb,
              const float* __restrict__ rw,
              const float* __restrict__ Wl,
              unsigned* __restrict__ Pq,
              unsigned* __restrict__ Wtq,
              float* __restrict__ qpart) {
    __shared__ float T[96][65];
    const int bx = blockIdx.x;
    const int tid = threadIdx.x;

    if (bx < 96) {
        const int i0 = bx * 4;
        const int j  = tid;
        float p[4];
        float s = 0.0f;
        #pragma unroll
        for (int ii = 0; ii < 4; ++ii) {
            const int i = i0 + ii;
            const int idx = i * DIM + j;
            float w0 = W[idx], w1 = W[SPLANE + idx], w2 = W[2 * SPLANE + idx];
            float b0 = Bb[idx], b1 = Bb[SPLANE + idx], b2 = Bb[2 * SPLANE + idx];
            float r1 = 1.0f - w1, r2 = 1.0f - w2;
            float r = rw[i];
            p[ii] = r * (1.0f - w0) * r1 * r2;
            s += r * (b0 * r1 * r2 + b1 * r2 + b2);
        }
        uint2 u;
        u.x = tobf(p[0]) | (tobf(p[1]) << 16);
        u.y = tobf(p[2]) | (tobf(p[3]) << 16);
        *(uint2*)&Pq[bx * 2 * DIM + 2 * j] = u;
        qpart[bx * DIM + j] = s;
    } else {
        const int b  = bx - 96;          // 0..23
        const int n0 = (b & 3) * 96;     // 4 groups of 96 output cols
        const int j0 = (b >> 2) * 64;    // 6 groups of 64 k's
        const int c  = tid & 63;         // j within tile
        const int r6 = tid >> 6;         // 0..5
        #pragma unroll
        for (int qq = 0; qq < 16; ++qq) {
            int row = r6 + 6 * qq;       // n within tile, 0..95
            T[row][c] = Wl[(n0 + row) * DIM + j0 + c];
        }
        __syncthreads();
        const int tn = tid % 96;
        const int q4 = tid / 96;         // 0..3
        #pragma unroll
        for (int cc = 0; cc < 4; ++cc) {
            int q = q4 + 4 * cc;         // j-quad within tile, 0..15
            uint2 u;
            u.x = tobf(T[tn][4 * q + 0]) | (tobf(T[tn][4 * q + 1]) << 16);
            u.y = tobf(T[tn][4 * q + 2]) | (tobf(T[tn][4 * q + 3]) << 16);
            *(uint2*)&Wtq[(j0 / 4 + q) * 2 * DIM + 2 * (n0 + tn)] = u;
        }
    }
}

// ---------------------------------------------------------------------------
// Kernel 2 (fused double-GEMM). 256 blocks x 384 threads, 4 batch rows/block.
//   stage 1: t[r][j] = sum_k v1[r][k]*Prw[k][j]; pooled = v2.*t - qc -> LDS
//   stage 2: out[r][n] = sum_j pooled[r][j]*lW[n][j] + lb[n]
// B streams are k-quad bf16 pairs: 1 dwordx2 load per 4 k per thread.
// A-operands are wave-uniform broadcast float4 LDS reads.
// ---------------------------------------------------------------------------
__global__ __launch_bounds__(384)
void fused_kernel(const float* __restrict__ v1,
                  const float* __restrict__ v2,
                  const unsigned* __restrict__ Pq,
                  const unsigned* __restrict__ Wtq,
                  const float* __restrict__ qpart,
                  const float* __restrict__ lb,
                  float* __restrict__ out) {
    __shared__ float AT[DIM][4];   // v1T: [k][r]
    __shared__ float PT[DIM][4];   // pooledT: [j][r]
    const int bm  = blockIdx.x * 4;
    const int tid = threadIdx.x;

    // stage v1 rows into AT[k][r]
    {
        const int r  = tid & 3;
        const int kq = tid >> 2;   // 0..95
        float4 a = *(const float4*)&v1[(bm + r) * DIM + 4 * kq];
        AT[4 * kq + 0][r] = a.x;
        AT[4 * kq + 1][r] = a.y;
        AT[4 * kq + 2][r] = a.z;
        AT[4 * kq + 3][r] = a.w;
    }

    // qc[tid] = sum of 96 deterministic partials (issued before the barrier,
    // latency overlaps the AT staging of other waves)
    float q0 = 0.f, q1 = 0.f;
    {
        const float* qp = qpart + tid;
        #pragma unroll 8
        for (int p = 0; p < 96; p += 2) {
            q0 += qp[p * DIM];
            q1 += qp[(p + 1) * DIM];
        }
    }
    const float qc = q0 + q1;
    __syncthreads();

    // ---- stage 1: thread owns column j = tid ----
    float a0 = 0.f, a1 = 0.f, a2 = 0.f, a3 = 0.f;
    {
        const unsigned* bp = Pq + 2 * tid;
        #pragma unroll 8
        for (int kq = 0; kq < 96; ++kq) {
            uint2 u = *(const uint2*)&bp[kq * 2 * DIM];
            float b0 = bflo(u.x), b1 = bfhi(u.x);
            float b2 = bflo(u.y), b3 = bfhi(u.y);
            float4 va = *(const float4*)&AT[4 * kq + 0][0];
            float4 vb = *(const float4*)&AT[4 * kq + 1][0];
            float4 vc = *(const float4*)&AT[4 * kq + 2][0];
            float4 vd = *(const float4*)&AT[4 * kq + 3][0];
            a0 += va.x * b0 + vb.x * b1 + vc.x * b2 + vd.x * b3;
            a1 += va.y * b0 + vb.y * b1 + vc.y * b2 + vd.y * b3;
            a2 += va.z * b0 + vb.z * b1 + vc.z * b2 + vd.z * b3;
            a3 += va.w * b0 + vb.w * b1 + vc.w * b2 + vd.w * b3;
        }
    }
    {
        float4 pv;
        pv.x = v2[(bm + 0) * DIM + tid] * a0 - qc;
        pv.y = v2[(bm + 1) * DIM + tid] * a1 - qc;
        pv.z = v2[(bm + 2) * DIM + tid] * a2 - qc;
        pv.w = v2[(bm + 3) * DIM + tid] * a3 - qc;
        *(float4*)&PT[tid][0] = pv;
    }
    __syncthreads();

    // ---- stage 2: thread owns output column n = tid ----
    float o0 = 0.f, o1 = 0.f, o2 = 0.f, o3 = 0.f;
    {
        const unsigned* wp = Wtq + 2 * tid;
        #pragma unroll 8
        for (int jq = 0; jq < 96; ++jq) {
            uint2 u = *(const uint2*)&wp[jq * 2 * DIM];
            float b0 = bflo(u.x), b1 = bfhi(u.x);
            float b2 = bflo(u.y), b3 = bfhi(u.y);
            float4 pa = *(const float4*)&PT[4 * jq + 0][0];
            float4 pb = *(const float4*)&PT[4 * jq + 1][0];
            float4 pc = *(const float4*)&PT[4 * jq + 2][0];
            float4 pd = *(const float4*)&PT[4 * jq + 3][0];
            o0 += pa.x * b0 + pb.x * b1 + pc.x * b2 + pd.x * b3;
            o1 += pa.y * b0 + pb.y * b1 + pc.y * b2 + pd.y * b3;
            o2 += pa.z * b0 + pb.z * b1 + pc.z * b2 + pd.z * b3;
            o3 += pa.w * b0 + pb.w * b1 + pc.w * b2 + pd.w * b3;
        }
    }
    {
        float b = lb[tid];
        out[(bm + 0) * DIM + tid] = o0 + b;
        out[(bm + 1) * DIM + tid] = o1 + b;
        out[(bm + 2) * DIM + tid] = o2 + b;
        out[(bm + 3) * DIM + tid] = o3 + b;
    }
}

extern "C" void kernel_launch(void* const* d_in, const int* in_sizes, int n_in,
                              void* d_out, int out_size, void* d_ws, size_t ws_size,
                              hipStream_t stream) {
    const float* v1  = (const float*)d_in[0];
    const float* v2  = (const float*)d_in[1];
    const float* bW  = (const float*)d_in[2];
    const float* bB  = (const float*)d_in[3];
    const float* rw  = (const float*)d_in[4];
    const float* lW  = (const float*)d_in[5];
    const float* lb  = (const float*)d_in[6];
    float* out = (float*)d_out;

    // workspace layout (bytes): Pq 288KB | Wtq 288KB | qpart 144KB
    unsigned* Pq    = (unsigned*)d_ws;
    unsigned* Wtq   = Pq + (DIM / 4) * 2 * DIM;
    float*    qpart = (float*)(Wtq + (DIM / 4) * 2 * DIM);

    prep_all<<<120, 384, 0, stream>>>(bW, bB, rw, lW, Pq, Wtq, qpart);
    fused_kernel<<<BATCH / 4, 384, 0, stream>>>(v1, v2, Pq, Wtq, qpart, lb, out);
}